// Round 6
// baseline (217.744 us; speedup 1.0000x reference)
//
#include <hip/hip_runtime.h>
#include <math.h>

static inline int cdiv(long long a, int b){ return (int)((a + b - 1) / b); }
#define DEVINL __device__ __forceinline__

DEVINL float4 relu4(const float* a){
  return make_float4(fmaxf(a[0],0.f), fmaxf(a[1],0.f), fmaxf(a[2],0.f), fmaxf(a[3],0.f));
}

DEVINL void load32(float* fv, const float* __restrict__ p){
#pragma unroll
  for (int q = 0; q < 8; ++q){
    float4 v = ((const float4*)p)[q];
    fv[4*q]=v.x; fv[4*q+1]=v.y; fv[4*q+2]=v.z; fv[4*q+3]=v.w;
  }
}
DEVINL void load8(float* fv, const float* __restrict__ p){
#pragma unroll
  for (int q = 0; q < 2; ++q){
    float4 v = ((const float4*)p)[q];
    fv[4*q]=v.x; fv[4*q+1]=v.y; fv[4*q+2]=v.z; fv[4*q+3]=v.w;
  }
}

// tap index for sibling pair: d = o' - o (componentwise), k = (dx+1)*9+(dy+1)*3+(dz+1)
DEVINL int sib_k(int o, int op){
  return 13 + 9*(((op>>2)&1) - ((o>>2)&1))
            + 3*(((op>>1)&1) - ((o>>1)&1))
            +   ((op&1) - (o&1));
}

// ---------- remainder list build: cross-parent valid neighbors only ----------
__global__ void k_rinit(int* __restrict__ cnt, int n){
  int i = blockIdx.x*blockDim.x + threadIdx.x;
  if (i < n) cnt[i] = 0;
}

__global__ void k_rbuild(const int* __restrict__ nin, const int* __restrict__ nout,
                         int* __restrict__ cnt, int* __restrict__ rem, int P, int N){
  int p = blockIdx.x*blockDim.x + threadIdx.x;
  if (p >= 27*P) return;
  int oi = nout[p];
  if (oi >= N) return;                 // padded slot
  int j = nin[p];
  if ((oi >> 3) == (j >> 3)) return;   // sibling: handled statically
  int k = p / P;
  int pos = atomicAdd(&cnt[oi], 1);
  rem[(size_t)oi*20 + pos] = (j << 5) | k;
}

// ---------- up: f[(n*8+kk)*32 + c0..3] = relu(x[n]·W_up[kk] + b_up) ----------
__global__ __launch_bounds__(256) void k_up(const float* __restrict__ x,
    const float* __restrict__ Wup, const float* __restrict__ bup,
    float* __restrict__ f, int Nn){
  __shared__ float Ws[64*32];
  const int kk = blockIdx.y;
  for (int e = threadIdx.x*4; e < 2048; e += 1024)
    *(float4*)&Ws[e] = *(const float4*)&Wup[(size_t)kk*2048 + e];
  __syncthreads();
  int t = threadIdx.x, cg = t & 7, nr = t >> 3;
  int n = blockIdx.x*32 + nr, c0 = cg*4;
  float4 b4 = *(const float4*)(bup + c0);
  float acc[4] = {b4.x, b4.y, b4.z, b4.w};
  float xr[64];
  const float4* xp = (const float4*)(x + (size_t)n*64);
#pragma unroll
  for (int q = 0; q < 16; ++q){
    float4 v = xp[q];
    xr[4*q]=v.x; xr[4*q+1]=v.y; xr[4*q+2]=v.z; xr[4*q+3]=v.w;
  }
#pragma unroll
  for (int cc = 0; cc < 64; ++cc){
    float4 w = *(const float4*)(Ws + cc*32 + c0);
    acc[0]=fmaf(xr[cc],w.x,acc[0]); acc[1]=fmaf(xr[cc],w.y,acc[1]);
    acc[2]=fmaf(xr[cc],w.z,acc[2]); acc[3]=fmaf(xr[cc],w.w,acc[3]);
  }
  *(float4*)(f + ((size_t)n*8 + kk)*32 + c0) = relu4(acc);
}

// ---------- conv1: 27x32x32, sibling-static; wave-uniform o; c-quarter per blockIdx.y ----------
// block 512 = 8 waves(=o) x [32 parents x 2 cg]; covers 256 rows x 8 outs
__global__ __launch_bounds__(512) void k_conv1(const float* __restrict__ fin,
    const float* __restrict__ Wg, const float* __restrict__ bg,
    const int* __restrict__ cnt, const int* __restrict__ rem,
    float* __restrict__ fout, int N){
  __shared__ float Ws[27*32*8];       // [k][cc][8], 27.6 KB
  const int cb = blockIdx.y*8;
  int t = threadIdx.x;
  for (int m = t; m < 1728; m += 512){
    int k = m >> 6, r = m & 63, cc = r >> 1, q = r & 1;
    *(float4*)&Ws[k*256 + cc*8 + q*4] =
      *(const float4*)&Wg[((size_t)(k*32 + cc))*32 + cb + q*4];
  }
  __syncthreads();
  int o = t >> 6, lane = t & 63, p = lane >> 1, cg = lane & 1;
  int base = blockIdx.x*256 + p*8;
  int row = base + o, c0 = cg*4;
  float4 b4 = *(const float4*)(bg + cb + c0);
  float acc[4] = {b4.x,b4.y,b4.z,b4.w};
  float fv[32];
#pragma unroll
  for (int op = 0; op < 8; ++op){
    int kk = sib_k(o, op);            // wave-uniform
    load32(fv, fin + (size_t)(base+op)*32);
    const float* wk = Ws + kk*256 + c0;
#pragma unroll
    for (int cc = 0; cc < 32; ++cc){
      float4 w = *(const float4*)(wk + cc*8);
      acc[0]=fmaf(fv[cc],w.x,acc[0]); acc[1]=fmaf(fv[cc],w.y,acc[1]);
      acc[2]=fmaf(fv[cc],w.z,acc[2]); acc[3]=fmaf(fv[cc],w.w,acc[3]);
    }
  }
  int nrm = cnt[row];
  for (int s = 0; s < nrm; ++s){
    int e = rem[(size_t)row*20 + s];
    int kk = e & 31, j = e >> 5;
    load32(fv, fin + (size_t)j*32);
    const float* wk = Ws + kk*256 + c0;
#pragma unroll
    for (int cc = 0; cc < 32; ++cc){
      float4 w = *(const float4*)(wk + cc*8);
      acc[0]=fmaf(fv[cc],w.x,acc[0]); acc[1]=fmaf(fv[cc],w.y,acc[1]);
      acc[2]=fmaf(fv[cc],w.z,acc[2]); acc[3]=fmaf(fv[cc],w.w,acc[3]);
    }
  }
  *(float4*)(fout + (size_t)row*32 + cb + c0) = relu4(acc);
}

// ---------- blk_a: a8 = relu(sconv32->8+b00); b8 = relu(f@W10+b10); wave-uniform o ----------
// block 512 = 8 waves(=o) x [32 parents x 2 cg]; covers 256 rows x 8 outs
__global__ __launch_bounds__(512) void k_blk_a(const float* __restrict__ fO,
    const float* __restrict__ W00, const float* __restrict__ b00,
    const float* __restrict__ W10, const float* __restrict__ b10,
    const int* __restrict__ cnt, const int* __restrict__ rem,
    float* __restrict__ a8, float* __restrict__ b8, int N){
  __shared__ float Ws[27*256 + 256];
  int t = threadIdx.x;
  for (int m = t; m < 1728; m += 512){
    int k = m >> 6, r = m & 63, cc = r >> 1, q = r & 1;
    *(float4*)&Ws[k*256 + cc*8 + q*4] = ((const float4*)W00)[m];
  }
  if (t < 64) *(float4*)&Ws[6912 + t*4] = ((const float4*)W10)[t];
  __syncthreads();
  int o = t >> 6, lane = t & 63, p = lane >> 1, cg = lane & 1;
  int base = blockIdx.x*256 + p*8;
  int row = base + o, c0 = cg*4;
  float4 b4 = *(const float4*)(b00 + c0);
  float acc[4] = {b4.x,b4.y,b4.z,b4.w};
  float fv[32];
#pragma unroll
  for (int op = 0; op < 8; ++op){
    int kk = sib_k(o, op);
    load32(fv, fO + (size_t)(base+op)*32);
    const float* wk = Ws + kk*256 + c0;
#pragma unroll
    for (int cc = 0; cc < 32; ++cc){
      float4 w = *(const float4*)(wk + cc*8);
      acc[0]=fmaf(fv[cc],w.x,acc[0]); acc[1]=fmaf(fv[cc],w.y,acc[1]);
      acc[2]=fmaf(fv[cc],w.z,acc[2]); acc[3]=fmaf(fv[cc],w.w,acc[3]);
    }
  }
  int nrm = cnt[row];
  for (int s = 0; s < nrm; ++s){
    int e = rem[(size_t)row*20 + s];
    int kk = e & 31, j = e >> 5;
    load32(fv, fO + (size_t)j*32);
    const float* wk = Ws + kk*256 + c0;
#pragma unroll
    for (int cc = 0; cc < 32; ++cc){
      float4 w = *(const float4*)(wk + cc*8);
      acc[0]=fmaf(fv[cc],w.x,acc[0]); acc[1]=fmaf(fv[cc],w.y,acc[1]);
      acc[2]=fmaf(fv[cc],w.z,acc[2]); acc[3]=fmaf(fv[cc],w.w,acc[3]);
    }
  }
  *(float4*)(a8 + (size_t)row*8 + c0) = relu4(acc);
  // dense branch on own row
  load32(fv, fO + (size_t)row*32);
  float4 d4 = *(const float4*)(b10 + c0);
  float accb[4] = {d4.x,d4.y,d4.z,d4.w};
#pragma unroll
  for (int cc = 0; cc < 32; ++cc){
    float4 w = *(const float4*)(Ws + 6912 + cc*8 + c0);
    accb[0]=fmaf(fv[cc],w.x,accb[0]); accb[1]=fmaf(fv[cc],w.y,accb[1]);
    accb[2]=fmaf(fv[cc],w.z,accb[2]); accb[3]=fmaf(fv[cc],w.w,accb[3]);
  }
  *(float4*)(b8 + (size_t)row*8 + c0) = relu4(accb);
}

// ---------- blk_b: fout[:,0:16] += sconv8->16(a8)+b01 ;
//            fout[:,16:32] += relu(sconv8->8(b8)+b11)@W12+b12 ; wave-uniform o ----------
// block 512 = 8 waves(=o) x [16 parents x 4 cg]; covers 128 rows x 16 outs
__global__ __launch_bounds__(512) void k_blk_b(const float* __restrict__ a8,
    const float* __restrict__ b8,
    const float* __restrict__ W01, const float* __restrict__ b01,
    const float* __restrict__ W11, const float* __restrict__ b11,
    const float* __restrict__ W12, const float* __restrict__ b12,
    const int* __restrict__ cnt, const int* __restrict__ rem,
    float* __restrict__ fout, int N){
  __shared__ float Ws[27*128 + 27*64 + 128];   // 3456 + 1728 + 128
  int t = threadIdx.x;
  for (int m = t; m < 864; m += 512)
    ((float4*)Ws)[m] = ((const float4*)W01)[m];
  for (int m = t; m < 432; m += 512)
    ((float4*)(Ws + 3456))[m] = ((const float4*)W11)[m];
  if (t < 32) *(float4*)&Ws[5184 + t*4] = ((const float4*)W12)[t];
  __syncthreads();
  int o = t >> 6, lane = t & 63, p = lane >> 2, cg = lane & 3;
  int base = blockIdx.x*128 + p*8;
  int row = base + o, c0 = cg*4;
  float4 b4 = *(const float4*)(b01 + c0);
  float acc0[4] = {b4.x,b4.y,b4.z,b4.w};
  float t8[8];
#pragma unroll
  for (int c = 0; c < 8; ++c) t8[c] = b11[c];
  float av[8], bv[8];
#pragma unroll
  for (int op = 0; op < 8; ++op){
    int kk = sib_k(o, op);
    load8(av, a8 + (size_t)(base+op)*8);
    load8(bv, b8 + (size_t)(base+op)*8);
    const float* w01k = Ws + kk*128 + c0;
    const float* w11k = Ws + 3456 + kk*64;
#pragma unroll
    for (int cc = 0; cc < 8; ++cc){
      float4 w = *(const float4*)(w01k + cc*16);
      acc0[0]=fmaf(av[cc],w.x,acc0[0]); acc0[1]=fmaf(av[cc],w.y,acc0[1]);
      acc0[2]=fmaf(av[cc],w.z,acc0[2]); acc0[3]=fmaf(av[cc],w.w,acc0[3]);
      float4 u0 = *(const float4*)(w11k + cc*8);
      float4 u1 = *(const float4*)(w11k + cc*8 + 4);
      t8[0]=fmaf(bv[cc],u0.x,t8[0]); t8[1]=fmaf(bv[cc],u0.y,t8[1]);
      t8[2]=fmaf(bv[cc],u0.z,t8[2]); t8[3]=fmaf(bv[cc],u0.w,t8[3]);
      t8[4]=fmaf(bv[cc],u1.x,t8[4]); t8[5]=fmaf(bv[cc],u1.y,t8[5]);
      t8[6]=fmaf(bv[cc],u1.z,t8[6]); t8[7]=fmaf(bv[cc],u1.w,t8[7]);
    }
  }
  int nrm = cnt[row];
  for (int s = 0; s < nrm; ++s){
    int e = rem[(size_t)row*20 + s];
    int kk = e & 31, j = e >> 5;
    load8(av, a8 + (size_t)j*8);
    load8(bv, b8 + (size_t)j*8);
    const float* w01k = Ws + kk*128 + c0;
    const float* w11k = Ws + 3456 + kk*64;
#pragma unroll
    for (int cc = 0; cc < 8; ++cc){
      float4 w = *(const float4*)(w01k + cc*16);
      acc0[0]=fmaf(av[cc],w.x,acc0[0]); acc0[1]=fmaf(av[cc],w.y,acc0[1]);
      acc0[2]=fmaf(av[cc],w.z,acc0[2]); acc0[3]=fmaf(av[cc],w.w,acc0[3]);
      float4 u0 = *(const float4*)(w11k + cc*8);
      float4 u1 = *(const float4*)(w11k + cc*8 + 4);
      t8[0]=fmaf(bv[cc],u0.x,t8[0]); t8[1]=fmaf(bv[cc],u0.y,t8[1]);
      t8[2]=fmaf(bv[cc],u0.z,t8[2]); t8[3]=fmaf(bv[cc],u0.w,t8[3]);
      t8[4]=fmaf(bv[cc],u1.x,t8[4]); t8[5]=fmaf(bv[cc],u1.y,t8[5]);
      t8[6]=fmaf(bv[cc],u1.z,t8[6]); t8[7]=fmaf(bv[cc],u1.w,t8[7]);
    }
  }
#pragma unroll
  for (int c = 0; c < 8; ++c) t8[c] = fmaxf(t8[c], 0.f);
  float4 d4 = *(const float4*)(b12 + c0);
  float acc1[4] = {d4.x,d4.y,d4.z,d4.w};
#pragma unroll
  for (int cc = 0; cc < 8; ++cc){
    float4 w = *(const float4*)(Ws + 5184 + cc*16 + c0);
    acc1[0]=fmaf(t8[cc],w.x,acc1[0]); acc1[1]=fmaf(t8[cc],w.y,acc1[1]);
    acc1[2]=fmaf(t8[cc],w.z,acc1[2]); acc1[3]=fmaf(t8[cc],w.w,acc1[3]);
  }
  float4* o0 = (float4*)(fout + (size_t)row*32 + c0);
  float4* o1 = (float4*)(fout + (size_t)row*32 + 16 + c0);
  float4 v0 = *o0, v1 = *o1;
  v0.x+=acc0[0]; v0.y+=acc0[1]; v0.z+=acc0[2]; v0.w+=acc0[3];
  v1.x+=acc1[0]; v1.y+=acc1[1]; v1.z+=acc1[2]; v1.w+=acc1[3];
  *o0 = v0; *o1 = v1;
}

// ---------- cls: 32->1 conv; wave-uniform o via (blockIdx.y*4 + wave) ----------
// block 256 = 4 waves x 64 parents; grid (N/512, 2)
__global__ __launch_bounds__(256) void k_cls(const float* __restrict__ fO,
    const float* __restrict__ Wc, const float* __restrict__ bc,
    const int* __restrict__ cnt, const int* __restrict__ rem,
    float* __restrict__ cls, int N){
  __shared__ float Ws[27*32];
  int t = threadIdx.x;
  if (t < 216) ((float4*)Ws)[t] = ((const float4*)Wc)[t];
  __syncthreads();
  int o = blockIdx.y*4 + (t >> 6), p = t & 63;
  int base = (blockIdx.x*64 + p)*8;
  int row = base + o;
  float acc = 0.f;
  float fv[32];
#pragma unroll
  for (int op = 0; op < 8; ++op){
    int kk = sib_k(o, op);
    load32(fv, fO + (size_t)(base+op)*32);
    const float* wk = Ws + kk*32;
#pragma unroll
    for (int c4 = 0; c4 < 8; ++c4){
      float4 w = *(const float4*)(wk + c4*4);
      acc = fmaf(fv[4*c4],w.x,acc);   acc = fmaf(fv[4*c4+1],w.y,acc);
      acc = fmaf(fv[4*c4+2],w.z,acc); acc = fmaf(fv[4*c4+3],w.w,acc);
    }
  }
  int nrm = cnt[row];
  for (int s = 0; s < nrm; ++s){
    int e = rem[(size_t)row*20 + s];
    int kk = e & 31, j = e >> 5;
    load32(fv, fO + (size_t)j*32);
    const float* wk = Ws + kk*32;
#pragma unroll
    for (int c4 = 0; c4 < 8; ++c4){
      float4 w = *(const float4*)(wk + c4*4);
      acc = fmaf(fv[4*c4],w.x,acc);   acc = fmaf(fv[4*c4+1],w.y,acc);
      acc = fmaf(fv[4*c4+2],w.z,acc); acc = fmaf(fv[4*c4+3],w.w,acc);
    }
  }
  cls[row] = acc + bc[0];
}

// ---------- max/argmax (first-index tie-break) ----------
__global__ void k_reduce1(const float* __restrict__ s, float* __restrict__ pmax,
                          int* __restrict__ pidx, int n){
  __shared__ float sm[256]; __shared__ int si[256];
  int t = threadIdx.x;
  float v = -INFINITY; int vi = 0x7fffffff;
  for (int j = blockIdx.x*256 + t; j < n; j += gridDim.x*256){
    float w = s[j];
    if (w > v){ v = w; vi = j; }
  }
  sm[t] = v; si[t] = vi; __syncthreads();
  for (int o = 128; o > 0; o >>= 1){
    if (t < o){
      if (sm[t+o] > sm[t] || (sm[t+o] == sm[t] && si[t+o] < si[t])){ sm[t]=sm[t+o]; si[t]=si[t+o]; }
    }
    __syncthreads();
  }
  if (t == 0){ pmax[blockIdx.x] = sm[0]; pidx[blockIdx.x] = si[0]; }
}

__global__ void k_reduce2(const float* __restrict__ pmax, const int* __restrict__ pidx,
                          float* __restrict__ g, int nb){
  __shared__ float sm[256]; __shared__ int si[256];
  int t = threadIdx.x;
  sm[t] = (t < nb) ? pmax[t] : -INFINITY;
  si[t] = (t < nb) ? pidx[t] : 0x7fffffff;
  __syncthreads();
  for (int o = 128; o > 0; o >>= 1){
    if (t < o){
      if (sm[t+o] > sm[t] || (sm[t+o] == sm[t] && si[t+o] < si[t])){ sm[t]=sm[t+o]; si[t]=si[t+o]; }
    }
    __syncthreads();
  }
  if (t == 0){ g[0] = sm[0]; ((int*)g)[1] = si[0]; }
}

// ---------- finalize ----------
__global__ void k_final(const float* __restrict__ out, const float* __restrict__ cls,
                        const int* __restrict__ target, const float* __restrict__ g,
                        float* __restrict__ dout, int n_out){
  int idx = blockIdx.x*blockDim.x + threadIdx.x;
  if (idx >= n_out*32) return;
  int row = idx >> 5, c = idx & 31;
  float s = cls[row];
  bool keep = s > 0.f;
  if (g[0] < 0.f) keep = keep || (row == ((const int*)g)[1]);
  float km = keep ? 1.f : 0.f;
  dout[idx] = out[idx] * km;
  if (c == 0){
    dout[(size_t)n_out*32 + row] = s;
    dout[(size_t)n_out*33 + row] = (target[row] != 0) ? 1.f : 0.f;
    dout[(size_t)n_out*34 + row] = km;
  }
}

extern "C" void kernel_launch(void* const* d_in, const int* in_sizes, int n_in,
                              void* d_out, int out_size, void* d_ws, size_t ws_size,
                              hipStream_t stream){
  const float* x      = (const float*)d_in[0];
  const float* W_up   = (const float*)d_in[1];
  const float* b_up   = (const float*)d_in[2];
  const float* W_conv = (const float*)d_in[3];
  const float* b_conv = (const float*)d_in[4];
  const float* Wb00   = (const float*)d_in[5];
  const float* bb00   = (const float*)d_in[6];
  const float* Wb01   = (const float*)d_in[7];
  const float* bb01   = (const float*)d_in[8];
  const float* Wb10   = (const float*)d_in[9];
  const float* bb10   = (const float*)d_in[10];
  const float* Wb11   = (const float*)d_in[11];
  const float* bb11   = (const float*)d_in[12];
  const float* Wb12   = (const float*)d_in[13];
  const float* bb12   = (const float*)d_in[14];
  const float* W_cls  = (const float*)d_in[15];
  const float* b_cls  = (const float*)d_in[16];
  const int*   nbr_in = (const int*)d_in[17];
  const int*   nbr_out= (const int*)d_in[18];
  const int*   target = (const int*)d_in[19];

  const int N = in_sizes[19];        // 65536
  const int P = in_sizes[17] / 27;
  const int pairsT = 27 * P;
  const int Nn = N / 8;              // 8192

  int*   cnt  = (int*)d_ws;                          // N
  int*   rem  = cnt + N;                             // N*20
  float* wsf  = (float*)(rem + (size_t)N*20);
  float* f_tmp = wsf;                                // N*32
  float* f_out = f_tmp + (size_t)N*32;               // N*32
  float* a8    = f_out + (size_t)N*32;               // N*8
  float* b8    = a8 + (size_t)N*8;                   // N*8
  float* cls   = b8 + (size_t)N*8;                   // N
  float* pmax  = cls + N;                            // 256
  int*   pidx  = (int*)(pmax + 256);                 // 256
  float* gm    = pmax + 512;                         // [max, argmax]

  const int B = 256;

  k_rinit<<<cdiv(N,B),B,0,stream>>>(cnt, N);
  k_rbuild<<<cdiv((long long)pairsT,B),B,0,stream>>>(nbr_in, nbr_out, cnt, rem, P, N);

  k_up<<<dim3(Nn/32,8),B,0,stream>>>(x, W_up, b_up, f_tmp, Nn);

  k_conv1<<<dim3(N/256,4),512,0,stream>>>(f_tmp, W_conv, b_conv, cnt, rem, f_out, N);

  for (int l = 0; l < 3; ++l){
    k_blk_a<<<N/256,512,0,stream>>>(f_out, Wb00 + (size_t)l*6912, bb00 + l*8,
                                    Wb10 + (size_t)l*256, bb10 + l*8, cnt, rem, a8, b8, N);
    k_blk_b<<<N/128,512,0,stream>>>(a8, b8,
                                    Wb01 + (size_t)l*3456, bb01 + l*16,
                                    Wb11 + (size_t)l*1728, bb11 + l*8,
                                    Wb12 + (size_t)l*128, bb12 + l*16,
                                    cnt, rem, f_out, N);
  }

  k_cls<<<dim3(N/512,2),B,0,stream>>>(f_out, W_cls, b_cls, cnt, rem, cls, N);

  k_reduce1<<<256,256,0,stream>>>(cls, pmax, pidx, N);
  k_reduce2<<<1,256,0,stream>>>(pmax, pidx, gm, 256);

  k_final<<<cdiv((long long)N*32,B),B,0,stream>>>(f_out, cls, target, gm, (float*)d_out, N);
}